// Round 6
// baseline (277.100 us; speedup 1.0000x reference)
//
#include <hip/hip_runtime.h>
#include <hip/hip_bf16.h>
#include <math.h>

#define DIM 1024
#define HID 64
#define SD  32
#define NS  64
#define TM  128
#define LRc 0.01f
#define EPSc 1e-8f

typedef __attribute__((ext_vector_type(8))) short bf16x8;
typedef __attribute__((ext_vector_type(4))) float f32x4;

__device__ __forceinline__ unsigned short f2bf(float f) {
    union { __hip_bfloat16 h; unsigned short u; } cv;
    cv.h = __float2bfloat16(f);
    return cv.u;
}
__device__ __forceinline__ float bf2f(unsigned short u) {
    union { unsigned short u; __hip_bfloat16 h; } cv;
    cv.u = u;
    return __bfloat162float(cv.h);
}

// ---------------- zero the global accumulator (64 x 33 floats) ----------------
__global__ __launch_bounds__(256) void zero_acc_kernel(float* __restrict__ gacc) {
    int i = blockIdx.x * 256 + threadIdx.x;
    if (i < NS * (SD + 1)) gacc[i] = 0.0f;
}

// ---------------- pack W1 -> bf16 hi/lo, MFMA-fragment order ----------------
// frag (kb, n): lane l, elem j  ->  W1[kb*32 + (l>>4)*8 + j][n*16 + (l&15)]
// stored lane-linear: idx = ((kb*4 + n)*64 + l)*8 + j   (each lane's 8 elems = 16B)
__global__ __launch_bounds__(256) void pack_w1_kernel(const float* __restrict__ W1,
                                                      unsigned short* __restrict__ W1h,
                                                      unsigned short* __restrict__ W1l) {
    int idx = blockIdx.x * 256 + threadIdx.x;   // 0..65535
    int j  = idx & 7;
    int l  = (idx >> 3) & 63;
    int n  = (idx >> 9) & 3;
    int kb = idx >> 11;
    int k  = kb * 32 + (l >> 4) * 8 + j;
    int c  = n * 16 + (l & 15);
    float w = W1[k * HID + c];
    unsigned short hu = f2bf(w);
    W1h[idx] = hu;
    W1l[idx] = f2bf(w - bf2f(hu));
}

// ---- A loads: raw float4; 4-deep rotation gives ~880cyc issue->use distance ----
__device__ __forceinline__ void load_A(float4 (&a)[2][2],
                                       const float* __restrict__ A0p,
                                       const float* __restrict__ A1p, int kb) {
    const int K0 = kb * 32;
    a[0][0] = *(const float4*)(A0p + K0);
    a[0][1] = *(const float4*)(A0p + K0 + 4);
    a[1][0] = *(const float4*)(A1p + K0);
    a[1][1] = *(const float4*)(A1p + K0 + 4);
}

// ---- B loads: 2-deep ping-pong (L2-resident, ~440cyc distance covers it) ----
__device__ __forceinline__ void load_B(bf16x8 (&bh)[4], bf16x8 (&bl)[4],
                                       const unsigned short* __restrict__ W1h,
                                       const unsigned short* __restrict__ W1l,
                                       int kb, int l) {
    const size_t fb = (size_t)kb * 2048 + (size_t)l * 8;  // (kb*4+n)*512 + l*8
    #pragma unroll
    for (int n = 0; n < 4; ++n) {
        bh[n] = *(const bf16x8*)(W1h + fb + (size_t)n * 512);
        bl[n] = *(const bf16x8*)(W1l + fb + (size_t)n * 512);
    }
}

__device__ __forceinline__ void cvt_split(const float4 a, const float4 b, bf16x8& hi, bf16x8& lo) {
    float f[8] = {a.x, a.y, a.z, a.w, b.x, b.y, b.z, b.w};
    #pragma unroll
    for (int j = 0; j < 8; ++j) {
        unsigned short hu = f2bf(f[j]);
        hi[j] = (short)hu;
        lo[j] = (short)f2bf(f[j] - bf2f(hu));
    }
}

__device__ __forceinline__ void comp_step(const float4 (&a)[2][2],
                                          const bf16x8 (&bh)[4], const bf16x8 (&bl)[4],
                                          f32x4 (&acc)[2][4]) {
    bf16x8 ah[2], al[2];
    cvt_split(a[0][0], a[0][1], ah[0], al[0]);
    cvt_split(a[1][0], a[1][1], ah[1], al[1]);
    #pragma unroll
    for (int m = 0; m < 2; ++m)
        #pragma unroll
        for (int n = 0; n < 4; ++n) {
            acc[m][n] = __builtin_amdgcn_mfma_f32_16x16x32_bf16(ah[m], bh[n], acc[m][n], 0, 0, 0);
            acc[m][n] = __builtin_amdgcn_mfma_f32_16x16x32_bf16(al[m], bh[n], acc[m][n], 0, 0, 0);
            acc[m][n] = __builtin_amdgcn_mfma_f32_16x16x32_bf16(ah[m], bl[n], acc[m][n], 0, 0, 0);
        }
}

// ---------------- main fused kernel: MFMA GEMM1 + encode + argmax + scatter ----------------
// Round-5 lesson: occupancy is capped by the 128-VGPR cliff (can't fit without
// spills) -> stay at 2 blocks/CU and buy latency tolerance with PIPELINE DEPTH:
// A 4-deep (HBM ~900cyc), B 2-deep ping-pong (L2 ~200-450cyc). ~190 VGPR, no cap.
__global__ __launch_bounds__(256, 2) void neo_main_kernel(
    const float* __restrict__ traces,
    const unsigned short* __restrict__ W1h, const unsigned short* __restrict__ W1l,
    const float* __restrict__ b1,     const float* __restrict__ W2,
    const float* __restrict__ b2,     const float* __restrict__ schemas,
    float* __restrict__ gacc)
{
    __shared__ union SM {
        float hs[TM][HID + 1];                                      // 33280 B (GEMM epilogue phase)
        struct { float Sn[NS][SD]; float accl[NS][SD + 1]; } p2;    // 16640 B (argmax phase)
    } sm;

    const int t  = threadIdx.x;
    const int l  = t & 63;
    const int wq = t >> 6;       // wave id 0..3 -> rows wq*32..wq*32+31
    const int lr = l & 15;       // row-in-frag (A) / col-in-frag (B,C)
    const int lg = l >> 4;       // k-group / C row-group

    // ---- GEMM1 via split-bf16 MFMA: (128 x 1024) @ (1024 x 64) ----
    const float* A0p = traces + (size_t)(blockIdx.x * TM + wq * 32 + lr) * DIM + lg * 8;
    const float* A1p = A0p + (size_t)16 * DIM;

    f32x4 acc[2][4];
    #pragma unroll
    for (int m = 0; m < 2; ++m)
        #pragma unroll
        for (int n = 0; n < 4; ++n) acc[m][n] = (f32x4){0.f, 0.f, 0.f, 0.f};

    float4 a0[2][2], a1[2][2], a2[2][2], a3[2][2];   // named slots: static indexing (no scratch)
    bf16x8 bh0[4], bl0[4], bh1[4], bl1[4];

    // prologue: fill the pipeline
    load_A(a0, A0p, A1p, 0);
    load_A(a1, A0p, A1p, 1);
    load_A(a2, A0p, A1p, 2);
    load_A(a3, A0p, A1p, 3);
    load_B(bh0, bl0, W1h, W1l, 0, l);
    load_B(bh1, bl1, W1h, W1l, 1, l);

    // steady state: 7 iterations of 4 steps (kb = 0..27)
    for (int kb = 0; kb < 28; kb += 4) {
        comp_step(a0, bh0, bl0, acc);
        load_A(a0, A0p, A1p, kb + 4);
        load_B(bh0, bl0, W1h, W1l, kb + 2, l);

        comp_step(a1, bh1, bl1, acc);
        load_A(a1, A0p, A1p, kb + 5);
        load_B(bh1, bl1, W1h, W1l, kb + 3, l);

        comp_step(a2, bh0, bl0, acc);
        load_A(a2, A0p, A1p, kb + 6);
        load_B(bh0, bl0, W1h, W1l, kb + 4, l);

        comp_step(a3, bh1, bl1, acc);
        load_A(a3, A0p, A1p, kb + 7);
        load_B(bh1, bl1, W1h, W1l, kb + 5, l);
    }
    // epilogue: kb = 28..31, no A prefetch (slots hold 28..31), B finishes 30,31
    comp_step(a0, bh0, bl0, acc);
    load_B(bh0, bl0, W1h, W1l, 30, l);
    comp_step(a1, bh1, bl1, acc);
    load_B(bh1, bl1, W1h, W1l, 31, l);
    comp_step(a2, bh0, bl0, acc);
    comp_step(a3, bh1, bl1, acc);

    // ---- h = relu(acc + b1) into LDS (MFMA C-layout: row=(l>>4)*4+r, col=n*16+(l&15)) ----
    {
        float b1v[4];
        #pragma unroll
        for (int n = 0; n < 4; ++n) b1v[n] = b1[n * 16 + lr];
        #pragma unroll
        for (int m = 0; m < 2; ++m)
            #pragma unroll
            for (int n = 0; n < 4; ++n)
                #pragma unroll
                for (int r = 0; r < 4; ++r) {
                    int row = wq * 32 + m * 16 + lg * 4 + r;
                    sm.hs[row][n * 16 + lr] = fmaxf(acc[m][n][r] + b1v[n], 0.0f);
                }
    }
    __syncthreads();

    // ---- encoded = h @ W2 + b2 : one thread per row, result stays in registers ----
    // W2 (8 KB) read lockstep-broadcast from global -> L1-resident.
    float enc[SD];
    if (t < TM) {
        #pragma unroll
        for (int c = 0; c < SD; ++c) enc[c] = b2[c];
        #pragma unroll 4
        for (int k = 0; k < HID; ++k) {
            float hk = sm.hs[t][k];
            #pragma unroll
            for (int c4 = 0; c4 < 8; ++c4) {
                float4 w = *(const float4*)(W2 + k * SD + c4 * 4);
                enc[c4 * 4 + 0] = fmaf(hk, w.x, enc[c4 * 4 + 0]);
                enc[c4 * 4 + 1] = fmaf(hk, w.y, enc[c4 * 4 + 1]);
                enc[c4 * 4 + 2] = fmaf(hk, w.z, enc[c4 * 4 + 2]);
                enc[c4 * 4 + 3] = fmaf(hk, w.w, enc[c4 * 4 + 3]);
            }
        }
    }
    __syncthreads();   // hs dead; union flips to {Sn, accl}

    // ---- normalized schemas + zero block-local accumulator ----
    if (t < NS) {
        float v[SD];
        float ss = 0.0f;
        #pragma unroll
        for (int c = 0; c < SD; ++c) { v[c] = schemas[t * SD + c]; ss += v[c] * v[c]; }
        float sc = 1.0f / fmaxf(sqrtf(ss), EPSc);
        #pragma unroll
        for (int c = 0; c < SD; ++c) sm.p2.Sn[t][c] = v[c] * sc;
    }
    for (int i = t; i < NS * (SD + 1); i += 256)
        (&sm.p2.accl[0][0])[i] = 0.0f;
    __syncthreads();

    // ---- argmax + block-local scatter (enc already in registers) ----
    if (t < TM) {
        // per-row positive normalization can't change argmax -> skip it
        float best = -INFINITY;
        int bi = 0;
        for (int s = 0; s < NS; ++s) {
            float d = 0.0f;
            #pragma unroll
            for (int c4 = 0; c4 < 8; ++c4) {
                float4 sv = *(const float4*)&sm.p2.Sn[s][c4 * 4];
                d = fmaf(enc[c4 * 4 + 0], sv.x, d);
                d = fmaf(enc[c4 * 4 + 1], sv.y, d);
                d = fmaf(enc[c4 * 4 + 2], sv.z, d);
                d = fmaf(enc[c4 * 4 + 3], sv.w, d);
            }
            if (d > best) { best = d; bi = s; }   // strict > keeps first max (jnp semantics)
        }
        atomicAdd(&sm.p2.accl[bi][SD], 1.0f);
        #pragma unroll
        for (int c = 0; c < SD; ++c) atomicAdd(&sm.p2.accl[bi][c], enc[c]);
    }
    __syncthreads();

    // ---- flush block partials to global accumulator ----
    for (int i = t; i < NS * (SD + 1); i += 256)
        atomicAdd(&gacc[i], (&sm.p2.accl[0][0])[i]);
}

// ---------------- finalize: schema update + stats ----------------
__global__ __launch_bounds__(64) void neo_finalize_kernel(
    const float* __restrict__ gacc, const float* __restrict__ schemas,
    const float* __restrict__ usage, float* __restrict__ out)
{
    const int s = threadIdx.x;   // 64 threads, 1 wave
    float count = gacc[s * (SD + 1) + SD];
    bool  ne    = count > 0.0f;
    float invc  = 1.0f / fmaxf(count, 1.0f);

    float nsq = 0.0f;
    #pragma unroll
    for (int c = 0; c < SD; ++c) {
        float sum    = gacc[s * (SD + 1) + c];
        float sch    = schemas[s * SD + c];
        float target = sum * invc;
        float delta  = ne ? (LRc * (target - sch)) : 0.0f;
        out[s * SD + c] = sch + delta;
        nsq = fmaf(delta, delta, nsq);
    }
    out[NS * SD + s] = usage[s] + count;

    float nrm = sqrtf(nsq);
    int nu = ne ? 1 : 0;
    #pragma unroll
    for (int off = 32; off > 0; off >>= 1) {
        nrm += __shfl_down(nrm, off);
        nu  += __shfl_down(nu, off);
    }
    if (s == 0) {
        out[NS * SD + NS]     = (float)nu;
        out[NS * SD + NS + 1] = nrm / (float)(nu > 0 ? nu : 1);
    }
}

extern "C" void kernel_launch(void* const* d_in, const int* in_sizes, int n_in,
                              void* d_out, int out_size, void* d_ws, size_t ws_size,
                              hipStream_t stream) {
    const float* traces  = (const float*)d_in[0];
    const float* W1      = (const float*)d_in[1];
    const float* b1      = (const float*)d_in[2];
    const float* W2      = (const float*)d_in[3];
    const float* b2      = (const float*)d_in[4];
    const float* schemas = (const float*)d_in[5];
    const float* usage   = (const float*)d_in[6];
    float* out  = (float*)d_out;

    float* gacc = (float*)d_ws;                                        // 8448 B
    unsigned short* W1h = (unsigned short*)((char*)d_ws + 16384);      // 128 KB
    unsigned short* W1l = (unsigned short*)((char*)d_ws + 16384 + 131072);

    const int N = in_sizes[0] / DIM;
    const int nblk = N / TM;

    hipLaunchKernelGGL(pack_w1_kernel, dim3(DIM * HID / 256), dim3(256), 0, stream, W1, W1h, W1l);
    hipLaunchKernelGGL(zero_acc_kernel, dim3((NS * (SD + 1) + 255) / 256), dim3(256), 0, stream, gacc);
    hipLaunchKernelGGL(neo_main_kernel, dim3(nblk), dim3(256), 0, stream,
                       traces, W1h, W1l, b1, W2, b2, schemas, gacc);
    hipLaunchKernelGGL(neo_finalize_kernel, dim3(1), dim3(64), 0, stream,
                       gacc, schemas, usage, out);
}

// Round 7
// 260.072 us; speedup vs baseline: 1.0655x; 1.0655x over previous
//
#include <hip/hip_runtime.h>
#include <hip/hip_bf16.h>
#include <math.h>

#define DIM 1024
#define HID 64
#define SD  32
#define NS  64
#define TM  128
#define LRc 0.01f
#define EPSc 1e-8f

typedef __attribute__((ext_vector_type(8))) short bf16x8;
typedef __attribute__((ext_vector_type(4))) float f32x4;

__device__ __forceinline__ unsigned short f2bf(float f) {
    union { __hip_bfloat16 h; unsigned short u; } cv;
    cv.h = __float2bfloat16(f);
    return cv.u;
}
__device__ __forceinline__ float bf2f(unsigned short u) {
    union { unsigned short u; __hip_bfloat16 h; } cv;
    cv.u = u;
    return __bfloat162float(cv.h);
}

// ---------------- zero the global accumulator (64 x 33 floats) ----------------
__global__ __launch_bounds__(256) void zero_acc_kernel(float* __restrict__ gacc) {
    int i = blockIdx.x * 256 + threadIdx.x;
    if (i < NS * (SD + 1)) gacc[i] = 0.0f;
}

// ---------------- pack W1 -> bf16 hi/lo, MFMA-fragment order ----------------
// PAIR-GRANULAR k-map (must match the A-load map in the main kernel):
//   frag kb (0..31), pair p = kb>>1, parity q = kb&1:
//   lane l, elem j  ->  k = p*64 + (l>>4)*16 + q*8 + j,  col = n*16 + (l&15)
// (contraction is invariant to the k<->(frag,lane,elem) permutation as long as
//  A and B use the SAME map; this map lets A load 16 CONSECUTIVE floats/lane)
// stored lane-linear: idx = ((kb*4 + n)*64 + l)*8 + j
__global__ __launch_bounds__(256) void pack_w1_kernel(const float* __restrict__ W1,
                                                      unsigned short* __restrict__ W1h,
                                                      unsigned short* __restrict__ W1l) {
    int idx = blockIdx.x * 256 + threadIdx.x;   // 0..65535
    int j  = idx & 7;
    int l  = (idx >> 3) & 63;
    int n  = (idx >> 9) & 3;
    int kb = idx >> 11;
    int k  = (kb >> 1) * 64 + (l >> 4) * 16 + (kb & 1) * 8 + j;
    int c  = n * 16 + (l & 15);
    float w = W1[k * HID + c];
    unsigned short hu = f2bf(w);
    W1h[idx] = hu;
    W1l[idx] = f2bf(w - bf2f(hu));
}

// ---- A loads: 16 consecutive floats per lane per pair (64 B contiguous burst) ----
__device__ __forceinline__ void load_pair(float4 (&a)[2][4],
                                          const float* __restrict__ A0p,
                                          const float* __restrict__ A1p, int p) {
    const int K0 = p * 64;
    #pragma unroll
    for (int i = 0; i < 4; ++i) a[0][i] = *(const float4*)(A0p + K0 + i * 4);
    #pragma unroll
    for (int i = 0; i < 4; ++i) a[1][i] = *(const float4*)(A1p + K0 + i * 4);
}

// ---- B loads: kb-granular, 2-deep ping-pong (round-3 proven scheme) ----
__device__ __forceinline__ void load_B(bf16x8 (&bh)[4], bf16x8 (&bl)[4],
                                       const unsigned short* __restrict__ W1h,
                                       const unsigned short* __restrict__ W1l,
                                       int kb, int l) {
    const size_t fb = (size_t)kb * 2048 + (size_t)l * 8;  // (kb*4+n)*512 + l*8
    #pragma unroll
    for (int n = 0; n < 4; ++n) {
        bh[n] = *(const bf16x8*)(W1h + fb + (size_t)n * 512);
        bl[n] = *(const bf16x8*)(W1l + fb + (size_t)n * 512);
    }
}

__device__ __forceinline__ void cvt_split(const float4 a, const float4 b, bf16x8& hi, bf16x8& lo) {
    float f[8] = {a.x, a.y, a.z, a.w, b.x, b.y, b.z, b.w};
    #pragma unroll
    for (int j = 0; j < 8; ++j) {
        unsigned short hu = f2bf(f[j]);
        hi[j] = (short)hu;
        lo[j] = (short)f2bf(f[j] - bf2f(hu));
    }
}

// one K-step (one kb) using half H of the pair slot (H=0: floats 0..7, H=1: 8..15)
template <int H>
__device__ __forceinline__ void comp_half(const float4 (&a)[2][4],
                                          const bf16x8 (&bh)[4], const bf16x8 (&bl)[4],
                                          f32x4 (&acc)[2][4]) {
    #pragma unroll
    for (int m = 0; m < 2; ++m) {
        bf16x8 ah, al;
        cvt_split(a[m][2 * H], a[m][2 * H + 1], ah, al);
        #pragma unroll
        for (int n = 0; n < 4; ++n) {
            acc[m][n] = __builtin_amdgcn_mfma_f32_16x16x32_bf16(ah, bh[n], acc[m][n], 0, 0, 0);
            acc[m][n] = __builtin_amdgcn_mfma_f32_16x16x32_bf16(al, bh[n], acc[m][n], 0, 0, 0);
            acc[m][n] = __builtin_amdgcn_mfma_f32_16x16x32_bf16(ah, bl[n], acc[m][n], 0, 0, 0);
        }
    }
}

// ---------------- main fused kernel: MFMA GEMM1 + encode + argmax + scatter ----------------
// Round-3 structure (best measured: 172.6us), single delta: pair-granular A
// loads (64B contiguous per lane, 2x issue->use distance). ~188 architected
// VGPR < 256 cap -> no spills. 2 blocks/CU (the 128-VGPR cliff makes higher
// occupancy unreachable without spills; rounds 4-6 proved that path regresses).
__global__ __launch_bounds__(256, 2) void neo_main_kernel(
    const float* __restrict__ traces,
    const unsigned short* __restrict__ W1h, const unsigned short* __restrict__ W1l,
    const float* __restrict__ b1,     const float* __restrict__ W2,
    const float* __restrict__ b2,     const float* __restrict__ schemas,
    float* __restrict__ gacc)
{
    __shared__ float hs[TM][HID + 1];     // 33280 B
    __shared__ float es[TM][SD + 1];      // 16896 B
    __shared__ float W2ls[HID][SD + 4];   //  9216 B
    __shared__ float Sn[NS][SD];          //  8192 B
    __shared__ float accl[NS][SD + 1];    //  8448 B

    const int t  = threadIdx.x;
    const int l  = t & 63;
    const int wq = t >> 6;       // wave id 0..3 -> rows wq*32..wq*32+31
    const int lr = l & 15;       // row-in-frag (A) / col-in-frag (B,C)
    const int lg = l >> 4;       // k-group / C row-group

    // ---- stage W2 into LDS ----
    for (int i = t; i < HID * SD; i += 256)
        W2ls[i / SD][i % SD] = W2[i];

    // ---- normalized schemas ----
    if (t < NS) {
        float v[SD];
        float ss = 0.0f;
        #pragma unroll
        for (int c = 0; c < SD; ++c) { v[c] = schemas[t * SD + c]; ss += v[c] * v[c]; }
        float sc = 1.0f / fmaxf(sqrtf(ss), EPSc);
        #pragma unroll
        for (int c = 0; c < SD; ++c) Sn[t][c] = v[c] * sc;
    }

    // ---- zero block-local accumulator ----
    for (int i = t; i < NS * (SD + 1); i += 256)
        (&accl[0][0])[i] = 0.0f;

    // ---- GEMM1 via split-bf16 MFMA: (128 x 1024) @ (1024 x 64) ----
    // lane base includes its 16-float window start: row*DIM + lg*16
    const float* A0p = traces + (size_t)(blockIdx.x * TM + wq * 32 + lr) * DIM + lg * 16;
    const float* A1p = A0p + (size_t)16 * DIM;

    f32x4 acc[2][4];
    #pragma unroll
    for (int m = 0; m < 2; ++m)
        #pragma unroll
        for (int n = 0; n < 4; ++n) acc[m][n] = (f32x4){0.f, 0.f, 0.f, 0.f};

    float4 sa0[2][4], sa1[2][4];           // pair slots (static names, no scratch)
    bf16x8 bhE[4], blE[4], bhO[4], blO[4]; // B ping-pong at kb granularity

    // prologue
    load_pair(sa0, A0p, A1p, 0);
    load_pair(sa1, A0p, A1p, 1);
    load_B(bhE, blE, W1h, W1l, 0, l);
    load_B(bhO, blO, W1h, W1l, 1, l);

    // 7 iterations x 2 pairs (pairs 0..13), epilogue pairs 14,15
    for (int p = 0; p < 14; p += 2) {
        comp_half<0>(sa0, bhE, blE, acc);
        load_B(bhE, blE, W1h, W1l, 2 * p + 2, l);
        comp_half<1>(sa0, bhO, blO, acc);
        load_B(bhO, blO, W1h, W1l, 2 * p + 3, l);
        load_pair(sa0, A0p, A1p, p + 2);

        comp_half<0>(sa1, bhE, blE, acc);
        load_B(bhE, blE, W1h, W1l, 2 * p + 4, l);
        comp_half<1>(sa1, bhO, blO, acc);
        load_B(bhO, blO, W1h, W1l, 2 * p + 5, l);
        load_pair(sa1, A0p, A1p, p + 3);
    }
    // pair 14 (B regs hold kb 28,29)
    comp_half<0>(sa0, bhE, blE, acc);
    load_B(bhE, blE, W1h, W1l, 30, l);
    comp_half<1>(sa0, bhO, blO, acc);
    load_B(bhO, blO, W1h, W1l, 31, l);
    // pair 15
    comp_half<0>(sa1, bhE, blE, acc);
    comp_half<1>(sa1, bhO, blO, acc);

    // ---- h = relu(acc + b1) into LDS (MFMA C-layout: row=(l>>4)*4+r, col=n*16+(l&15)) ----
    {
        float b1v[4];
        #pragma unroll
        for (int n = 0; n < 4; ++n) b1v[n] = b1[n * 16 + lr];
        #pragma unroll
        for (int m = 0; m < 2; ++m)
            #pragma unroll
            for (int n = 0; n < 4; ++n)
                #pragma unroll
                for (int r = 0; r < 4; ++r) {
                    int row = wq * 32 + m * 16 + lg * 4 + r;
                    hs[row][n * 16 + lr] = fmaxf(acc[m][n][r] + b1v[n], 0.0f);
                }
    }
    __syncthreads();

    // ---- encoded = h @ W2 + b2 : thread handles (row r, 16-col half) ----
    {
        const int r = t >> 1;
        const int half = t & 1;
        const int c0 = half * 16;
        float enc[16];
        #pragma unroll
        for (int j = 0; j < 16; ++j) enc[j] = 0.0f;
        for (int k = 0; k < HID; ++k) {
            float hk = hs[r][k];
            #pragma unroll
            for (int c4 = 0; c4 < 4; ++c4) {
                float4 w = *(const float4*)&W2ls[k][c0 + c4 * 4];
                enc[c4 * 4 + 0] = fmaf(hk, w.x, enc[c4 * 4 + 0]);
                enc[c4 * 4 + 1] = fmaf(hk, w.y, enc[c4 * 4 + 1]);
                enc[c4 * 4 + 2] = fmaf(hk, w.z, enc[c4 * 4 + 2]);
                enc[c4 * 4 + 3] = fmaf(hk, w.w, enc[c4 * 4 + 3]);
            }
        }
        #pragma unroll
        for (int j = 0; j < 16; ++j) {
            enc[j] += b2[c0 + j];
            es[r][c0 + j] = enc[j];
        }
    }
    __syncthreads();

    // ---- sims + argmax + block-local scatter (one thread per row) ----
    if (t < TM) {
        float e[SD];
        #pragma unroll
        for (int c = 0; c < SD; ++c) e[c] = es[t][c];

        // per-row positive normalization can't change argmax -> skip it
        float best = -INFINITY;
        int bi = 0;
        for (int s = 0; s < NS; ++s) {
            float d = 0.0f;
            #pragma unroll
            for (int c4 = 0; c4 < 8; ++c4) {
                float4 sv = *(const float4*)&Sn[s][c4 * 4];
                d = fmaf(e[c4 * 4 + 0], sv.x, d);
                d = fmaf(e[c4 * 4 + 1], sv.y, d);
                d = fmaf(e[c4 * 4 + 2], sv.z, d);
                d = fmaf(e[c4 * 4 + 3], sv.w, d);
            }
            if (d > best) { best = d; bi = s; }   // strict > keeps first max (jnp semantics)
        }
        atomicAdd(&accl[bi][SD], 1.0f);
        #pragma unroll
        for (int c = 0; c < SD; ++c) atomicAdd(&accl[bi][c], e[c]);
    }
    __syncthreads();

    // ---- flush block partials to global accumulator ----
    for (int i = t; i < NS * (SD + 1); i += 256)
        atomicAdd(&gacc[i], (&accl[0][0])[i]);
}

// ---------------- finalize: schema update + stats ----------------
__global__ __launch_bounds__(64) void neo_finalize_kernel(
    const float* __restrict__ gacc, const float* __restrict__ schemas,
    const float* __restrict__ usage, float* __restrict__ out)
{
    const int s = threadIdx.x;   // 64 threads, 1 wave
    float count = gacc[s * (SD + 1) + SD];
    bool  ne    = count > 0.0f;
    float invc  = 1.0f / fmaxf(count, 1.0f);

    float nsq = 0.0f;
    #pragma unroll
    for (int c = 0; c < SD; ++c) {
        float sum    = gacc[s * (SD + 1) + c];
        float sch    = schemas[s * SD + c];
        float target = sum * invc;
        float delta  = ne ? (LRc * (target - sch)) : 0.0f;
        out[s * SD + c] = sch + delta;
        nsq = fmaf(delta, delta, nsq);
    }
    out[NS * SD + s] = usage[s] + count;

    float nrm = sqrtf(nsq);
    int nu = ne ? 1 : 0;
    #pragma unroll
    for (int off = 32; off > 0; off >>= 1) {
        nrm += __shfl_down(nrm, off);
        nu  += __shfl_down(nu, off);
    }
    if (s == 0) {
        out[NS * SD + NS]     = (float)nu;
        out[NS * SD + NS + 1] = nrm / (float)(nu > 0 ? nu : 1);
    }
}

extern "C" void kernel_launch(void* const* d_in, const int* in_sizes, int n_in,
                              void* d_out, int out_size, void* d_ws, size_t ws_size,
                              hipStream_t stream) {
    const float* traces  = (const float*)d_in[0];
    const float* W1      = (const float*)d_in[1];
    const float* b1      = (const float*)d_in[2];
    const float* W2      = (const float*)d_in[3];
    const float* b2      = (const float*)d_in[4];
    const float* schemas = (const float*)d_in[5];
    const float* usage   = (const float*)d_in[6];
    float* out  = (float*)d_out;

    float* gacc = (float*)d_ws;                                        // 8448 B
    unsigned short* W1h = (unsigned short*)((char*)d_ws + 16384);      // 128 KB
    unsigned short* W1l = (unsigned short*)((char*)d_ws + 16384 + 131072);

    const int N = in_sizes[0] / DIM;
    const int nblk = N / TM;

    hipLaunchKernelGGL(pack_w1_kernel, dim3(DIM * HID / 256), dim3(256), 0, stream, W1, W1h, W1l);
    hipLaunchKernelGGL(zero_acc_kernel, dim3((NS * (SD + 1) + 255) / 256), dim3(256), 0, stream, gacc);
    hipLaunchKernelGGL(neo_main_kernel, dim3(nblk), dim3(256), 0, stream,
                       traces, W1h, W1l, b1, W2, b2, schemas, gacc);
    hipLaunchKernelGGL(neo_finalize_kernel, dim3(1), dim3(64), 0, stream,
                       gacc, schemas, usage, out);
}

// Round 8
// 227.256 us; speedup vs baseline: 1.2193x; 1.1444x over previous
//
#include <hip/hip_runtime.h>
#include <hip/hip_bf16.h>
#include <math.h>

#define DIM 1024
#define HID 64
#define SD  32
#define NS  64
#define TM  128
#define NC  32          // K-chunks of 32
#define LRc 0.01f
#define EPSc 1e-8f

typedef __attribute__((ext_vector_type(8))) short bf16x8;
typedef __attribute__((ext_vector_type(4))) float f32x4;

__device__ __forceinline__ unsigned short f2bf(float f) {
    union { __hip_bfloat16 h; unsigned short u; } cv;
    cv.h = __float2bfloat16(f);
    return cv.u;
}
__device__ __forceinline__ float bf2f(unsigned short u) {
    union { unsigned short u; __hip_bfloat16 h; } cv;
    cv.u = u;
    return __bfloat162float(cv.h);
}

// ---------------- zero the global accumulator (64 x 33 floats) ----------------
__global__ __launch_bounds__(256) void zero_acc_kernel(float* __restrict__ gacc) {
    int i = blockIdx.x * 256 + threadIdx.x;
    if (i < NS * (SD + 1)) gacc[i] = 0.0f;
}

// ---------------- pack W1 -> bf16 hi/lo, MFMA-fragment order (round-3 map) ----
// frag (kb, n): lane l, elem j  ->  W1[kb*32 + (l>>4)*8 + j][n*16 + (l&15)]
// stored lane-linear: idx = ((kb*4 + n)*64 + l)*8 + j
__global__ __launch_bounds__(256) void pack_w1_kernel(const float* __restrict__ W1,
                                                      unsigned short* __restrict__ W1h,
                                                      unsigned short* __restrict__ W1l) {
    int idx = blockIdx.x * 256 + threadIdx.x;   // 0..65535
    int j  = idx & 7;
    int l  = (idx >> 3) & 63;
    int n  = (idx >> 9) & 3;
    int kb = idx >> 11;
    int k  = kb * 32 + (l >> 4) * 8 + j;
    int c  = n * 16 + (l & 15);
    float w = W1[k * HID + c];
    unsigned short hu = f2bf(w);
    W1h[idx] = hu;
    W1l[idx] = f2bf(w - bf2f(hu));
}

__device__ __forceinline__ void cvt_split(const float4 a, const float4 b, bf16x8& hi, bf16x8& lo) {
    float f[8] = {a.x, a.y, a.z, a.w, b.x, b.y, b.z, b.w};
    #pragma unroll
    for (int j = 0; j < 8; ++j) {
        unsigned short hu = f2bf(f[j]);
        hi[j] = (short)hu;
        lo[j] = (short)f2bf(f[j] - bf2f(hu));
    }
}

// ---------------- main fused kernel: LDS-staged MFMA GEMM1 + epilogue ----------------
// T14 async-stage structure: per chunk {ds_write regs -> LDS | issue next-chunk
// global loads | lgkmcnt(0) | s_barrier | compute}. One barrier per chunk; the
// WAR on the 2-deep LDS buffer is separated by the PREVIOUS chunk's barrier.
// A fragment reads use XOR swizzle (piece ^= row&7) applied on the GLOBAL
// source at stage time and on the ds_read — both sides (rule 21).
__global__ __launch_bounds__(256, 3) void neo_main_kernel(
    const float* __restrict__ traces,
    const unsigned short* __restrict__ W1h, const unsigned short* __restrict__ W1l,
    const float* __restrict__ b1,     const float* __restrict__ W2,
    const float* __restrict__ b2,     const float* __restrict__ schemas,
    float* __restrict__ gacc)
{
    __shared__ __align__(16) union SM {
        struct { char A[2][16384]; char B[2][8192]; } g;            // 48 KB GEMM stage
        float hs[TM][HID + 1];                                      // 33.3 KB epilogue ph1
        struct { float Sn[NS][SD]; float accl[NS][SD + 1]; } p2;    // 16.6 KB epilogue ph2
    } sm;

    const int t  = threadIdx.x;
    const int l  = t & 63;
    const int wq = t >> 6;       // wave id 0..3 -> rows wq*32..wq*32+31
    const int lr = l & 15;       // row-in-frag (A) / col-in-frag (B,C)
    const int lg = l >> 4;       // k-group
    const long rowbase = (long)blockIdx.x * TM;

    // ---- per-thread A staging sources (global piece is XOR-swizzled) ----
    // slot i = it*256+t -> row=i>>3, pslot=i&7; source piece sp = pslot ^ (row&7)
    const float* srcA[4];
    #pragma unroll
    for (int it = 0; it < 4; ++it) {
        int i   = it * 256 + t;
        int row = i >> 3;
        int sp  = (i & 7) ^ (row & 7);
        srcA[it] = traces + (rowbase + row) * DIM + sp * 4;
    }
    const unsigned short* srcBh = W1h + (size_t)t * 8;
    const unsigned short* srcBl = W1l + (size_t)t * 8;

    f32x4 acc[2][4];
    #pragma unroll
    for (int m = 0; m < 2; ++m)
        #pragma unroll
        for (int n = 0; n < 4; ++n) acc[m][n] = (f32x4){0.f, 0.f, 0.f, 0.f};

#define LOADC(RA, RBH, RBL, c)                                                  \
    {                                                                           \
        _Pragma("unroll")                                                       \
        for (int it = 0; it < 4; ++it) RA[it] = *(const float4*)(srcA[it] + (c) * 32); \
        RBH = *(const bf16x8*)(srcBh + (size_t)(c) * 2048);                     \
        RBL = *(const bf16x8*)(srcBl + (size_t)(c) * 2048);                     \
    }

#define WRITEC(CUR, RA, RBH, RBL)                                               \
    {                                                                           \
        _Pragma("unroll")                                                       \
        for (int it = 0; it < 4; ++it)                                          \
            *(float4*)&sm.g.A[CUR][(it * 256 + t) * 16] = RA[it];               \
        *(bf16x8*)&sm.g.B[CUR][t * 16] = RBH;                                   \
        *(bf16x8*)&sm.g.B[CUR][4096 + t * 16] = RBL;                            \
    }

#define COMPUTE(CUR)                                                            \
    {                                                                           \
        bf16x8 vbh0 = *(const bf16x8*)&sm.g.B[CUR][0 * 1024 + l * 16];          \
        bf16x8 vbh1 = *(const bf16x8*)&sm.g.B[CUR][1 * 1024 + l * 16];          \
        bf16x8 vbh2 = *(const bf16x8*)&sm.g.B[CUR][2 * 1024 + l * 16];          \
        bf16x8 vbh3 = *(const bf16x8*)&sm.g.B[CUR][3 * 1024 + l * 16];          \
        bf16x8 vbl0 = *(const bf16x8*)&sm.g.B[CUR][4096 + 0 * 1024 + l * 16];   \
        bf16x8 vbl1 = *(const bf16x8*)&sm.g.B[CUR][4096 + 1 * 1024 + l * 16];   \
        bf16x8 vbl2 = *(const bf16x8*)&sm.g.B[CUR][4096 + 2 * 1024 + l * 16];   \
        bf16x8 vbl3 = *(const bf16x8*)&sm.g.B[CUR][4096 + 3 * 1024 + l * 16];   \
        _Pragma("unroll")                                                       \
        for (int m = 0; m < 2; ++m) {                                           \
            int row = wq * 32 + m * 16 + lr;                                    \
            int rs  = row & 7;                                                  \
            int q   = 2 * lg;                                                   \
            float4 x = *(const float4*)&sm.g.A[CUR][row * 128 + ((q    ) ^ rs) * 16]; \
            float4 y = *(const float4*)&sm.g.A[CUR][row * 128 + ((q + 1) ^ rs) * 16]; \
            bf16x8 ah, al;                                                      \
            cvt_split(x, y, ah, al);                                            \
            acc[m][0] = __builtin_amdgcn_mfma_f32_16x16x32_bf16(ah, vbh0, acc[m][0], 0, 0, 0); \
            acc[m][0] = __builtin_amdgcn_mfma_f32_16x16x32_bf16(al, vbh0, acc[m][0], 0, 0, 0); \
            acc[m][0] = __builtin_amdgcn_mfma_f32_16x16x32_bf16(ah, vbl0, acc[m][0], 0, 0, 0); \
            acc[m][1] = __builtin_amdgcn_mfma_f32_16x16x32_bf16(ah, vbh1, acc[m][1], 0, 0, 0); \
            acc[m][1] = __builtin_amdgcn_mfma_f32_16x16x32_bf16(al, vbh1, acc[m][1], 0, 0, 0); \
            acc[m][1] = __builtin_amdgcn_mfma_f32_16x16x32_bf16(ah, vbl1, acc[m][1], 0, 0, 0); \
            acc[m][2] = __builtin_amdgcn_mfma_f32_16x16x32_bf16(ah, vbh2, acc[m][2], 0, 0, 0); \
            acc[m][2] = __builtin_amdgcn_mfma_f32_16x16x32_bf16(al, vbh2, acc[m][2], 0, 0, 0); \
            acc[m][2] = __builtin_amdgcn_mfma_f32_16x16x32_bf16(ah, vbl2, acc[m][2], 0, 0, 0); \
            acc[m][3] = __builtin_amdgcn_mfma_f32_16x16x32_bf16(ah, vbh3, acc[m][3], 0, 0, 0); \
            acc[m][3] = __builtin_amdgcn_mfma_f32_16x16x32_bf16(al, vbh3, acc[m][3], 0, 0, 0); \
            acc[m][3] = __builtin_amdgcn_mfma_f32_16x16x32_bf16(ah, vbl3, acc[m][3], 0, 0, 0); \
        }                                                                       \
    }

#define SYNC()                                                                  \
    asm volatile("s_waitcnt lgkmcnt(0)" ::: "memory");                          \
    __builtin_amdgcn_s_barrier();

    float4 rA0[4], rA1[4];
    bf16x8 rBh0, rBl0, rBh1, rBl1;

    LOADC(rA0, rBh0, rBl0, 0);
    for (int c = 0; c < NC; c += 2) {
        WRITEC(0, rA0, rBh0, rBl0);                 // compiler waits the reg deps (vmcnt)
        if (c + 1 < NC) LOADC(rA1, rBh1, rBl1, c + 1);
        SYNC();
        COMPUTE(0);

        WRITEC(1, rA1, rBh1, rBl1);
        if (c + 2 < NC) LOADC(rA0, rBh0, rBl0, c + 2);
        SYNC();
        COMPUTE(1);
    }
    __syncthreads();   // GEMM buffers dead; union flips to hs

    // ---- h = relu(acc + b1) into LDS (MFMA C-layout: row=(l>>4)*4+r, col=n*16+(l&15)) ----
    {
        float b1v[4];
        #pragma unroll
        for (int n = 0; n < 4; ++n) b1v[n] = b1[n * 16 + lr];
        #pragma unroll
        for (int m = 0; m < 2; ++m)
            #pragma unroll
            for (int n = 0; n < 4; ++n)
                #pragma unroll
                for (int r = 0; r < 4; ++r) {
                    int row = wq * 32 + m * 16 + lg * 4 + r;
                    sm.hs[row][n * 16 + lr] = fmaxf(acc[m][n][r] + b1v[n], 0.0f);
                }
    }
    __syncthreads();

    // ---- encoded = h @ W2 + b2 : one thread per row, result stays in registers ----
    // W2 (8 KB) read lockstep-broadcast from global -> L1/L2-resident.
    float enc[SD];
    if (t < TM) {
        #pragma unroll
        for (int c = 0; c < SD; ++c) enc[c] = b2[c];
        #pragma unroll 4
        for (int k = 0; k < HID; ++k) {
            float hk = sm.hs[t][k];
            #pragma unroll
            for (int c4 = 0; c4 < 8; ++c4) {
                float4 w = *(const float4*)(W2 + k * SD + c4 * 4);
                enc[c4 * 4 + 0] = fmaf(hk, w.x, enc[c4 * 4 + 0]);
                enc[c4 * 4 + 1] = fmaf(hk, w.y, enc[c4 * 4 + 1]);
                enc[c4 * 4 + 2] = fmaf(hk, w.z, enc[c4 * 4 + 2]);
                enc[c4 * 4 + 3] = fmaf(hk, w.w, enc[c4 * 4 + 3]);
            }
        }
    }
    __syncthreads();   // hs dead; union flips to {Sn, accl}

    // ---- normalized schemas + zero block-local accumulator ----
    if (t < NS) {
        float v[SD];
        float ss = 0.0f;
        #pragma unroll
        for (int c = 0; c < SD; ++c) { v[c] = schemas[t * SD + c]; ss += v[c] * v[c]; }
        float sc = 1.0f / fmaxf(sqrtf(ss), EPSc);
        #pragma unroll
        for (int c = 0; c < SD; ++c) sm.p2.Sn[t][c] = v[c] * sc;
    }
    for (int i = t; i < NS * (SD + 1); i += 256)
        (&sm.p2.accl[0][0])[i] = 0.0f;
    __syncthreads();

    // ---- argmax + block-local scatter (enc already in registers) ----
    if (t < TM) {
        // per-row positive normalization can't change argmax -> skip it
        float best = -INFINITY;
        int bi = 0;
        for (int s = 0; s < NS; ++s) {
            float d = 0.0f;
            #pragma unroll
            for (int c4 = 0; c4 < 8; ++c4) {
                float4 sv = *(const float4*)&sm.p2.Sn[s][c4 * 4];
                d = fmaf(enc[c4 * 4 + 0], sv.x, d);
                d = fmaf(enc[c4 * 4 + 1], sv.y, d);
                d = fmaf(enc[c4 * 4 + 2], sv.z, d);
                d = fmaf(enc[c4 * 4 + 3], sv.w, d);
            }
            if (d > best) { best = d; bi = s; }   // strict > keeps first max (jnp semantics)
        }
        atomicAdd(&sm.p2.accl[bi][SD], 1.0f);
        #pragma unroll
        for (int c = 0; c < SD; ++c) atomicAdd(&sm.p2.accl[bi][c], enc[c]);
    }
    __syncthreads();

    // ---- flush block partials to global accumulator ----
    for (int i = t; i < NS * (SD + 1); i += 256)
        atomicAdd(&gacc[i], (&sm.p2.accl[0][0])[i]);
}

// ---------------- finalize: schema update + stats ----------------
__global__ __launch_bounds__(64) void neo_finalize_kernel(
    const float* __restrict__ gacc, const float* __restrict__ schemas,
    const float* __restrict__ usage, float* __restrict__ out)
{
    const int s = threadIdx.x;   // 64 threads, 1 wave
    float count = gacc[s * (SD + 1) + SD];
    bool  ne    = count > 0.0f;
    float invc  = 1.0f / fmaxf(count, 1.0f);

    float nsq = 0.0f;
    #pragma unroll
    for (int c = 0; c < SD; ++c) {
        float sum    = gacc[s * (SD + 1) + c];
        float sch    = schemas[s * SD + c];
        float target = sum * invc;
        float delta  = ne ? (LRc * (target - sch)) : 0.0f;
        out[s * SD + c] = sch + delta;
        nsq = fmaf(delta, delta, nsq);
    }
    out[NS * SD + s] = usage[s] + count;

    float nrm = sqrtf(nsq);
    int nu = ne ? 1 : 0;
    #pragma unroll
    for (int off = 32; off > 0; off >>= 1) {
        nrm += __shfl_down(nrm, off);
        nu  += __shfl_down(nu, off);
    }
    if (s == 0) {
        out[NS * SD + NS]     = (float)nu;
        out[NS * SD + NS + 1] = nrm / (float)(nu > 0 ? nu : 1);
    }
}

extern "C" void kernel_launch(void* const* d_in, const int* in_sizes, int n_in,
                              void* d_out, int out_size, void* d_ws, size_t ws_size,
                              hipStream_t stream) {
    const float* traces  = (const float*)d_in[0];
    const float* W1      = (const float*)d_in[1];
    const float* b1      = (const float*)d_in[2];
    const float* W2      = (const float*)d_in[3];
    const float* b2      = (const float*)d_in[4];
    const float* schemas = (const float*)d_in[5];
    const float* usage   = (const float*)d_in[6];
    float* out  = (float*)d_out;

    float* gacc = (float*)d_ws;                                        // 8448 B
    unsigned short* W1h = (unsigned short*)((char*)d_ws + 16384);      // 128 KB
    unsigned short* W1l = (unsigned short*)((char*)d_ws + 16384 + 131072);

    const int N = in_sizes[0] / DIM;
    const int nblk = N / TM;

    hipLaunchKernelGGL(pack_w1_kernel, dim3(DIM * HID / 256), dim3(256), 0, stream, W1, W1h, W1l);
    hipLaunchKernelGGL(zero_acc_kernel, dim3((NS * (SD + 1) + 255) / 256), dim3(256), 0, stream, gacc);
    hipLaunchKernelGGL(neo_main_kernel, dim3(nblk), dim3(256), 0, stream,
                       traces, W1h, W1l, b1, W2, b2, schemas, gacc);
    hipLaunchKernelGGL(neo_finalize_kernel, dim3(1), dim3(64), 0, stream,
                       gacc, schemas, usage, out);
}

// Round 9
// 189.609 us; speedup vs baseline: 1.4614x; 1.1985x over previous
//
#include <hip/hip_runtime.h>
#include <hip/hip_bf16.h>
#include <math.h>

#define DIM 1024
#define HID 64
#define SD  32
#define NS  64
#define TM  128
#define NACC (NS * (SD + 1))   // 2112
#define LRc 0.01f
#define EPSc 1e-8f

typedef __attribute__((ext_vector_type(8))) short bf16x8;
typedef __attribute__((ext_vector_type(4))) float f32x4;

__device__ __forceinline__ unsigned short f2bf(float f) {
    union { __hip_bfloat16 h; unsigned short u; } cv;
    cv.h = __float2bfloat16(f);
    return cv.u;
}
__device__ __forceinline__ float bf2f(unsigned short u) {
    union { unsigned short u; __hip_bfloat16 h; } cv;
    cv.u = u;
    return __bfloat162float(cv.h);
}

// ---------------- pack W1 -> bf16 hi/lo, MFMA-fragment order (round-3 map) ----
// frag (kb, n): lane l, elem j  ->  W1[kb*32 + (l>>4)*8 + j][n*16 + (l&15)]
// stored lane-linear: idx = ((kb*4 + n)*64 + l)*8 + j   (each lane's 8 elems = 16B)
__global__ __launch_bounds__(256) void pack_w1_kernel(const float* __restrict__ W1,
                                                      unsigned short* __restrict__ W1h,
                                                      unsigned short* __restrict__ W1l) {
    int idx = blockIdx.x * 256 + threadIdx.x;   // 0..65535
    int j  = idx & 7;
    int l  = (idx >> 3) & 63;
    int n  = (idx >> 9) & 3;
    int kb = idx >> 11;
    int k  = kb * 32 + (l >> 4) * 8 + j;
    int c  = n * 16 + (l & 15);
    float w = W1[k * HID + c];
    unsigned short hu = f2bf(w);
    W1h[idx] = hu;
    W1l[idx] = f2bf(w - bf2f(hu));
}

struct StepBuf {
    float4 a[2][2];        // [row-frag m][k-half]
    bf16x8 bh[4], bl[4];   // [col-frag n]
};

__device__ __forceinline__ void load_step(StepBuf& s,
                                          const float* __restrict__ A0p, const float* __restrict__ A1p,
                                          const unsigned short* __restrict__ W1h,
                                          const unsigned short* __restrict__ W1l,
                                          int kb, int l) {
    const int K0 = kb * 32;
    s.a[0][0] = *(const float4*)(A0p + K0);
    s.a[0][1] = *(const float4*)(A0p + K0 + 4);
    s.a[1][0] = *(const float4*)(A1p + K0);
    s.a[1][1] = *(const float4*)(A1p + K0 + 4);
    const size_t fb = (size_t)kb * 2048 + (size_t)l * 8;  // (kb*4+n)*512 + l*8
    #pragma unroll
    for (int n = 0; n < 4; ++n) {
        s.bh[n] = *(const bf16x8*)(W1h + fb + (size_t)n * 512);
        s.bl[n] = *(const bf16x8*)(W1l + fb + (size_t)n * 512);
    }
}

__device__ __forceinline__ void cvt_split(const float4 a, const float4 b, bf16x8& hi, bf16x8& lo) {
    float f[8] = {a.x, a.y, a.z, a.w, b.x, b.y, b.z, b.w};
    #pragma unroll
    for (int j = 0; j < 8; ++j) {
        unsigned short hu = f2bf(f[j]);
        hi[j] = (short)hu;
        lo[j] = (short)f2bf(f[j] - bf2f(hu));
    }
}

__device__ __forceinline__ void comp_step(const StepBuf& s, f32x4 (&acc)[2][4]) {
    bf16x8 ah[2], al[2];
    #pragma unroll
    for (int m = 0; m < 2; ++m) cvt_split(s.a[m][0], s.a[m][1], ah[m], al[m]);
    #pragma unroll
    for (int m = 0; m < 2; ++m)
        #pragma unroll
        for (int n = 0; n < 4; ++n) {
            acc[m][n] = __builtin_amdgcn_mfma_f32_16x16x32_bf16(ah[m], s.bh[n], acc[m][n], 0, 0, 0);
            acc[m][n] = __builtin_amdgcn_mfma_f32_16x16x32_bf16(al[m], s.bh[n], acc[m][n], 0, 0, 0);
            acc[m][n] = __builtin_amdgcn_mfma_f32_16x16x32_bf16(ah[m], s.bl[n], acc[m][n], 0, 0, 0);
        }
}

// ---------------- main fused kernel: ROUND-3 STRUCTURE VERBATIM ----------------
// Single delta vs round 3 (best measured 172.6us): the global ATOMIC flush is
// replaced by a per-block PARTIAL STORE (part[block][2112], coalesced, zero
// contention). Rounds 4-8 proved GEMM-loop restructures all regress; this
// isolates the epilogue-atomic hypothesis (~2.16M same-address atomics).
__global__ __launch_bounds__(256, 2) void neo_main_kernel(
    const float* __restrict__ traces,
    const unsigned short* __restrict__ W1h, const unsigned short* __restrict__ W1l,
    const float* __restrict__ b1,     const float* __restrict__ W2,
    const float* __restrict__ b2,     const float* __restrict__ schemas,
    float* __restrict__ part)
{
    __shared__ float hs[TM][HID + 1];     // 33280 B
    __shared__ float es[TM][SD + 1];      // 16896 B
    __shared__ float W2ls[HID][SD + 4];   //  9216 B
    __shared__ float Sn[NS][SD];          //  8192 B
    __shared__ float accl[NS][SD + 1];    //  8448 B

    const int t  = threadIdx.x;
    const int l  = t & 63;
    const int wq = t >> 6;       // wave id 0..3 -> rows wq*32..wq*32+31
    const int lr = l & 15;       // row-in-frag (A) / col-in-frag (B,C)
    const int lg = l >> 4;       // k-group / C row-group

    // ---- stage W2 into LDS ----
    for (int i = t; i < HID * SD; i += 256)
        W2ls[i / SD][i % SD] = W2[i];

    // ---- normalized schemas ----
    if (t < NS) {
        float v[SD];
        float ss = 0.0f;
        #pragma unroll
        for (int c = 0; c < SD; ++c) { v[c] = schemas[t * SD + c]; ss += v[c] * v[c]; }
        float sc = 1.0f / fmaxf(sqrtf(ss), EPSc);
        #pragma unroll
        for (int c = 0; c < SD; ++c) Sn[t][c] = v[c] * sc;
    }

    // ---- zero block-local accumulator ----
    for (int i = t; i < NACC; i += 256)
        (&accl[0][0])[i] = 0.0f;

    // ---- GEMM1 via split-bf16 MFMA: (128 x 1024) @ (1024 x 64) ----
    const float* A0p = traces + (size_t)(blockIdx.x * TM + wq * 32 + lr) * DIM + lg * 8;
    const float* A1p = A0p + (size_t)16 * DIM;

    f32x4 acc[2][4];
    #pragma unroll
    for (int m = 0; m < 2; ++m)
        #pragma unroll
        for (int n = 0; n < 4; ++n) acc[m][n] = (f32x4){0.f, 0.f, 0.f, 0.f};

    StepBuf s0, s1;
    load_step(s0, A0p, A1p, W1h, W1l, 0, l);
    for (int kb = 0; kb < 32; kb += 2) {
        load_step(s1, A0p, A1p, W1h, W1l, kb + 1, l);
        comp_step(s0, acc);
        if (kb + 2 < 32) load_step(s0, A0p, A1p, W1h, W1l, kb + 2, l);
        comp_step(s1, acc);
    }

    // ---- h = relu(acc + b1) into LDS (MFMA C-layout: row=(l>>4)*4+r, col=n*16+(l&15)) ----
    {
        float b1v[4];
        #pragma unroll
        for (int n = 0; n < 4; ++n) b1v[n] = b1[n * 16 + lr];
        #pragma unroll
        for (int m = 0; m < 2; ++m)
            #pragma unroll
            for (int n = 0; n < 4; ++n)
                #pragma unroll
                for (int r = 0; r < 4; ++r) {
                    int row = wq * 32 + m * 16 + lg * 4 + r;
                    hs[row][n * 16 + lr] = fmaxf(acc[m][n][r] + b1v[n], 0.0f);
                }
    }
    __syncthreads();

    // ---- encoded = h @ W2 + b2 : thread handles (row r, 16-col half) ----
    {
        const int r = t >> 1;
        const int half = t & 1;
        const int c0 = half * 16;
        float enc[16];
        #pragma unroll
        for (int j = 0; j < 16; ++j) enc[j] = 0.0f;
        for (int k = 0; k < HID; ++k) {
            float hk = hs[r][k];
            #pragma unroll
            for (int c4 = 0; c4 < 4; ++c4) {
                float4 w = *(const float4*)&W2ls[k][c0 + c4 * 4];
                enc[c4 * 4 + 0] = fmaf(hk, w.x, enc[c4 * 4 + 0]);
                enc[c4 * 4 + 1] = fmaf(hk, w.y, enc[c4 * 4 + 1]);
                enc[c4 * 4 + 2] = fmaf(hk, w.z, enc[c4 * 4 + 2]);
                enc[c4 * 4 + 3] = fmaf(hk, w.w, enc[c4 * 4 + 3]);
            }
        }
        #pragma unroll
        for (int j = 0; j < 16; ++j) {
            enc[j] += b2[c0 + j];
            es[r][c0 + j] = enc[j];
        }
    }
    __syncthreads();

    // ---- sims + argmax + block-local scatter (one thread per row) ----
    if (t < TM) {
        float e[SD];
        #pragma unroll
        for (int c = 0; c < SD; ++c) e[c] = es[t][c];

        // per-row positive normalization can't change argmax -> skip it
        float best = -INFINITY;
        int bi = 0;
        for (int s = 0; s < NS; ++s) {
            float d = 0.0f;
            #pragma unroll
            for (int c4 = 0; c4 < 8; ++c4) {
                float4 sv = *(const float4*)&Sn[s][c4 * 4];
                d = fmaf(e[c4 * 4 + 0], sv.x, d);
                d = fmaf(e[c4 * 4 + 1], sv.y, d);
                d = fmaf(e[c4 * 4 + 2], sv.z, d);
                d = fmaf(e[c4 * 4 + 3], sv.w, d);
            }
            if (d > best) { best = d; bi = s; }   // strict > keeps first max (jnp semantics)
        }
        atomicAdd(&accl[bi][SD], 1.0f);
        #pragma unroll
        for (int c = 0; c < SD; ++c) atomicAdd(&accl[bi][c], e[c]);
    }
    __syncthreads();

    // ---- flush block partials: PLAIN coalesced stores to this block's slot ----
    {
        float* myp = part + (size_t)blockIdx.x * NACC;
        for (int i = t; i < NACC; i += 256)
            myp[i] = (&accl[0][0])[i];
    }
}

// ---------------- reduce: part[nblk][2112] -> red[8][2112] ----------------
__global__ __launch_bounds__(256) void reduce_part_kernel(const float* __restrict__ part,
                                                          float* __restrict__ red, int nblk) {
    int i = blockIdx.x * 256 + threadIdx.x;    // value index 0..2111 (grid.x = 9)
    int g = blockIdx.y;                        // group 0..7
    if (i >= NACC) return;
    const int per = nblk >> 3;                 // 128
    int b0 = g * per, b1 = b0 + per;
    float s0 = 0.f, s1 = 0.f, s2 = 0.f, s3 = 0.f;
    int b = b0;
    for (; b + 3 < b1; b += 4) {
        s0 += part[(size_t)(b + 0) * NACC + i];
        s1 += part[(size_t)(b + 1) * NACC + i];
        s2 += part[(size_t)(b + 2) * NACC + i];
        s3 += part[(size_t)(b + 3) * NACC + i];
    }
    for (; b < b1; ++b) s0 += part[(size_t)b * NACC + i];
    red[(size_t)g * NACC + i] = (s0 + s1) + (s2 + s3);
}

// ---------------- finalize: schema update + stats (sums the 8 groups) ----------------
__global__ __launch_bounds__(64) void neo_finalize_kernel(
    const float* __restrict__ red, const float* __restrict__ schemas,
    const float* __restrict__ usage, float* __restrict__ out)
{
    const int s = threadIdx.x;   // 64 threads, 1 wave
    float count = 0.0f;
    #pragma unroll
    for (int g = 0; g < 8; ++g) count += red[(size_t)g * NACC + s * (SD + 1) + SD];
    bool  ne    = count > 0.0f;
    float invc  = 1.0f / fmaxf(count, 1.0f);

    float nsq = 0.0f;
    #pragma unroll
    for (int c = 0; c < SD; ++c) {
        float sum = 0.0f;
        #pragma unroll
        for (int g = 0; g < 8; ++g) sum += red[(size_t)g * NACC + s * (SD + 1) + c];
        float sch    = schemas[s * SD + c];
        float target = sum * invc;
        float delta  = ne ? (LRc * (target - sch)) : 0.0f;
        out[s * SD + c] = sch + delta;
        nsq = fmaf(delta, delta, nsq);
    }
    out[NS * SD + s] = usage[s] + count;

    float nrm = sqrtf(nsq);
    int nu = ne ? 1 : 0;
    #pragma unroll
    for (int off = 32; off > 0; off >>= 1) {
        nrm += __shfl_down(nrm, off);
        nu  += __shfl_down(nu, off);
    }
    if (s == 0) {
        out[NS * SD + NS]     = (float)nu;
        out[NS * SD + NS + 1] = nrm / (float)(nu > 0 ? nu : 1);
    }
}

extern "C" void kernel_launch(void* const* d_in, const int* in_sizes, int n_in,
                              void* d_out, int out_size, void* d_ws, size_t ws_size,
                              hipStream_t stream) {
    const float* traces  = (const float*)d_in[0];
    const float* W1      = (const float*)d_in[1];
    const float* b1      = (const float*)d_in[2];
    const float* W2      = (const float*)d_in[3];
    const float* b2      = (const float*)d_in[4];
    const float* schemas = (const float*)d_in[5];
    const float* usage   = (const float*)d_in[6];
    float* out  = (float*)d_out;

    unsigned short* W1h = (unsigned short*)((char*)d_ws + 16384);          // 128 KB
    unsigned short* W1l = (unsigned short*)((char*)d_ws + 16384 + 131072); // 128 KB
    float* part = (float*)((char*)d_ws + (1 << 20));                       // nblk*2112*4 = 8.65 MB
    float* red  = (float*)((char*)d_ws + (16 << 20));                      // 8*2112*4 = 67.6 KB

    const int N = in_sizes[0] / DIM;
    const int nblk = N / TM;   // 1024

    hipLaunchKernelGGL(pack_w1_kernel, dim3(DIM * HID / 256), dim3(256), 0, stream, W1, W1h, W1l);
    hipLaunchKernelGGL(neo_main_kernel, dim3(nblk), dim3(256), 0, stream,
                       traces, W1h, W1l, b1, W2, b2, schemas, part);
    hipLaunchKernelGGL(reduce_part_kernel, dim3((NACC + 255) / 256, 8), dim3(256), 0, stream,
                       part, red, nblk);
    hipLaunchKernelGGL(neo_finalize_kernel, dim3(1), dim3(64), 0, stream,
                       red, schemas, usage, out);
}

// Round 10
// 170.155 us; speedup vs baseline: 1.6285x; 1.1143x over previous
//
#include <hip/hip_runtime.h>
#include <hip/hip_bf16.h>
#include <math.h>

#define DIM 1024
#define HID 64
#define SD  32
#define NS  64
#define TM  128
#define LRc 0.01f
#define EPSc 1e-8f

typedef __attribute__((ext_vector_type(8))) short bf16x8;
typedef __attribute__((ext_vector_type(4))) float f32x4;

__device__ __forceinline__ unsigned short f2bf(float f) {
    union { __hip_bfloat16 h; unsigned short u; } cv;
    cv.h = __float2bfloat16(f);
    return cv.u;
}
__device__ __forceinline__ float bf2f(unsigned short u) {
    union { unsigned short u; __hip_bfloat16 h; } cv;
    cv.u = u;
    return __bfloat162float(cv.h);
}

// ---------------- zero the global accumulator (64 x 33 floats) ----------------
__global__ __launch_bounds__(256) void zero_acc_kernel(float* __restrict__ gacc) {
    int i = blockIdx.x * 256 + threadIdx.x;
    if (i < NS * (SD + 1)) gacc[i] = 0.0f;
}

// ---------------- pack W1 -> bf16 hi/lo, MFMA-fragment order (round-3 map) ----
// frag (kb, n): lane l, elem j  ->  W1[kb*32 + (l>>4)*8 + j][n*16 + (l&15)]
// stored lane-linear: idx = ((kb*4 + n)*64 + l)*8 + j   (each lane's 8 elems = 16B)
__global__ __launch_bounds__(256) void pack_w1_kernel(const float* __restrict__ W1,
                                                      unsigned short* __restrict__ W1h,
                                                      unsigned short* __restrict__ W1l) {
    int idx = blockIdx.x * 256 + threadIdx.x;   // 0..65535
    int j  = idx & 7;
    int l  = (idx >> 3) & 63;
    int n  = (idx >> 9) & 3;
    int kb = idx >> 11;
    int k  = kb * 32 + (l >> 4) * 8 + j;
    int c  = n * 16 + (l & 15);
    float w = W1[k * HID + c];
    unsigned short hu = f2bf(w);
    W1h[idx] = hu;
    W1l[idx] = f2bf(w - bf2f(hu));
}

struct StepBuf {
    float4 a[2][2];        // [row-frag m][k-half]
    bf16x8 bh[4], bl[4];   // [col-frag n]
};

__device__ __forceinline__ void load_step(StepBuf& s,
                                          const float* __restrict__ A0p, const float* __restrict__ A1p,
                                          const unsigned short* __restrict__ W1h,
                                          const unsigned short* __restrict__ W1l,
                                          int kb, int l) {
    const int K0 = kb * 32;
    s.a[0][0] = *(const float4*)(A0p + K0);
    s.a[0][1] = *(const float4*)(A0p + K0 + 4);
    s.a[1][0] = *(const float4*)(A1p + K0);
    s.a[1][1] = *(const float4*)(A1p + K0 + 4);
    const size_t fb = (size_t)kb * 2048 + (size_t)l * 8;  // (kb*4+n)*512 + l*8
    #pragma unroll
    for (int n = 0; n < 4; ++n) {
        s.bh[n] = *(const bf16x8*)(W1h + fb + (size_t)n * 512);
        s.bl[n] = *(const bf16x8*)(W1l + fb + (size_t)n * 512);
    }
}

__device__ __forceinline__ void cvt_split(const float4 a, const float4 b, bf16x8& hi, bf16x8& lo) {
    float f[8] = {a.x, a.y, a.z, a.w, b.x, b.y, b.z, b.w};
    #pragma unroll
    for (int j = 0; j < 8; ++j) {
        unsigned short hu = f2bf(f[j]);
        hi[j] = (short)hu;
        lo[j] = (short)f2bf(f[j] - bf2f(hu));
    }
}

__device__ __forceinline__ void comp_step(const StepBuf& s, f32x4 (&acc)[2][4]) {
    bf16x8 ah[2], al[2];
    #pragma unroll
    for (int m = 0; m < 2; ++m) cvt_split(s.a[m][0], s.a[m][1], ah[m], al[m]);
    #pragma unroll
    for (int m = 0; m < 2; ++m)
        #pragma unroll
        for (int n = 0; n < 4; ++n) {
            acc[m][n] = __builtin_amdgcn_mfma_f32_16x16x32_bf16(ah[m], s.bh[n], acc[m][n], 0, 0, 0);
            acc[m][n] = __builtin_amdgcn_mfma_f32_16x16x32_bf16(al[m], s.bh[n], acc[m][n], 0, 0, 0);
            acc[m][n] = __builtin_amdgcn_mfma_f32_16x16x32_bf16(ah[m], s.bl[n], acc[m][n], 0, 0, 0);
        }
}

// ---------------- main fused kernel: MFMA GEMM1 + encode + argmax + scatter ----------------
// ROUND-3 GEMM LOOP VERBATIM (A+B double-buffered StepBuf — every loop
// restructure in rounds 4-9 regressed). Only delta: LDS diet 76->33.3 KB
// (union + enc-in-registers + W2 from global, validated rounds 5-8) so LDS no
// longer caps occupancy, and launch_bounds(256,3) -> VGPR cap 170 (loop needs
// ~160; round-4's 128 cap spilled). 3 blocks/CU = 12 waves vs round-3's 8.
__global__ __launch_bounds__(256, 3) void neo_main_kernel(
    const float* __restrict__ traces,
    const unsigned short* __restrict__ W1h, const unsigned short* __restrict__ W1l,
    const float* __restrict__ b1,     const float* __restrict__ W2,
    const float* __restrict__ b2,     const float* __restrict__ schemas,
    float* __restrict__ gacc)
{
    __shared__ union SM {
        float hs[TM][HID + 1];                                      // 33280 B (GEMM epilogue phase)
        struct { float Sn[NS][SD]; float accl[NS][SD + 1]; } p2;    // 16640 B (argmax phase)
    } sm;

    const int t  = threadIdx.x;
    const int l  = t & 63;
    const int wq = t >> 6;       // wave id 0..3 -> rows wq*32..wq*32+31
    const int lr = l & 15;       // row-in-frag (A) / col-in-frag (B,C)
    const int lg = l >> 4;       // k-group / C row-group

    // ---- GEMM1 via split-bf16 MFMA: (128 x 1024) @ (1024 x 64) ----
    const float* A0p = traces + (size_t)(blockIdx.x * TM + wq * 32 + lr) * DIM + lg * 8;
    const float* A1p = A0p + (size_t)16 * DIM;

    f32x4 acc[2][4];
    #pragma unroll
    for (int m = 0; m < 2; ++m)
        #pragma unroll
        for (int n = 0; n < 4; ++n) acc[m][n] = (f32x4){0.f, 0.f, 0.f, 0.f};

    StepBuf s0, s1;
    load_step(s0, A0p, A1p, W1h, W1l, 0, l);
    for (int kb = 0; kb < 32; kb += 2) {
        load_step(s1, A0p, A1p, W1h, W1l, kb + 1, l);
        comp_step(s0, acc);
        if (kb + 2 < 32) load_step(s0, A0p, A1p, W1h, W1l, kb + 2, l);
        comp_step(s1, acc);
    }

    // ---- h = relu(acc + b1) into LDS (MFMA C-layout: row=(l>>4)*4+r, col=n*16+(l&15)) ----
    {
        float b1v[4];
        #pragma unroll
        for (int n = 0; n < 4; ++n) b1v[n] = b1[n * 16 + lr];
        #pragma unroll
        for (int m = 0; m < 2; ++m)
            #pragma unroll
            for (int n = 0; n < 4; ++n)
                #pragma unroll
                for (int r = 0; r < 4; ++r) {
                    int row = wq * 32 + m * 16 + lg * 4 + r;
                    sm.hs[row][n * 16 + lr] = fmaxf(acc[m][n][r] + b1v[n], 0.0f);
                }
    }
    __syncthreads();

    // ---- encoded = h @ W2 + b2 : one thread per row, result stays in registers ----
    // W2 (8 KB) read lockstep-broadcast from global -> L1-resident.
    float enc[SD];
    if (t < TM) {
        #pragma unroll
        for (int c = 0; c < SD; ++c) enc[c] = b2[c];
        #pragma unroll 4
        for (int k = 0; k < HID; ++k) {
            float hk = sm.hs[t][k];
            #pragma unroll
            for (int c4 = 0; c4 < 8; ++c4) {
                float4 w = *(const float4*)(W2 + k * SD + c4 * 4);
                enc[c4 * 4 + 0] = fmaf(hk, w.x, enc[c4 * 4 + 0]);
                enc[c4 * 4 + 1] = fmaf(hk, w.y, enc[c4 * 4 + 1]);
                enc[c4 * 4 + 2] = fmaf(hk, w.z, enc[c4 * 4 + 2]);
                enc[c4 * 4 + 3] = fmaf(hk, w.w, enc[c4 * 4 + 3]);
            }
        }
    }
    __syncthreads();   // hs dead; union flips to {Sn, accl}

    // ---- normalized schemas + zero block-local accumulator ----
    if (t < NS) {
        float v[SD];
        float ss = 0.0f;
        #pragma unroll
        for (int c = 0; c < SD; ++c) { v[c] = schemas[t * SD + c]; ss += v[c] * v[c]; }
        float sc = 1.0f / fmaxf(sqrtf(ss), EPSc);
        #pragma unroll
        for (int c = 0; c < SD; ++c) sm.p2.Sn[t][c] = v[c] * sc;
    }
    for (int i = t; i < NS * (SD + 1); i += 256)
        (&sm.p2.accl[0][0])[i] = 0.0f;
    __syncthreads();

    // ---- argmax + block-local scatter (enc already in registers) ----
    if (t < TM) {
        // per-row positive normalization can't change argmax -> skip it
        float best = -INFINITY;
        int bi = 0;
        for (int s = 0; s < NS; ++s) {
            float d = 0.0f;
            #pragma unroll
            for (int c4 = 0; c4 < 8; ++c4) {
                float4 sv = *(const float4*)&sm.p2.Sn[s][c4 * 4];
                d = fmaf(enc[c4 * 4 + 0], sv.x, d);
                d = fmaf(enc[c4 * 4 + 1], sv.y, d);
                d = fmaf(enc[c4 * 4 + 2], sv.z, d);
                d = fmaf(enc[c4 * 4 + 3], sv.w, d);
            }
            if (d > best) { best = d; bi = s; }   // strict > keeps first max (jnp semantics)
        }
        atomicAdd(&sm.p2.accl[bi][SD], 1.0f);
        #pragma unroll
        for (int c = 0; c < SD; ++c) atomicAdd(&sm.p2.accl[bi][c], enc[c]);
    }
    __syncthreads();

    // ---- flush block partials to global accumulator (round-3 scheme: atomics
    //      are cheap/overlapped; round-9 partial-store alternative was SLOWER) ----
    for (int i = t; i < NS * (SD + 1); i += 256)
        atomicAdd(&gacc[i], (&sm.p2.accl[0][0])[i]);
}

// ---------------- finalize: schema update + stats ----------------
__global__ __launch_bounds__(64) void neo_finalize_kernel(
    const float* __restrict__ gacc, const float* __restrict__ schemas,
    const float* __restrict__ usage, float* __restrict__ out)
{
    const int s = threadIdx.x;   // 64 threads, 1 wave
    float count = gacc[s * (SD + 1) + SD];
    bool  ne    = count > 0.0f;
    float invc  = 1.0f / fmaxf(count, 1.0f);

    float nsq = 0.0f;
    #pragma unroll
    for (int c = 0; c < SD; ++c) {
        float sum    = gacc[s * (SD + 1) + c];
        float sch    = schemas[s * SD + c];
        float target = sum * invc;
        float delta  = ne ? (LRc * (target - sch)) : 0.0f;
        out[s * SD + c] = sch + delta;
        nsq = fmaf(delta, delta, nsq);
    }
    out[NS * SD + s] = usage[s] + count;

    float nrm = sqrtf(nsq);
    int nu = ne ? 1 : 0;
    #pragma unroll
    for (int off = 32; off > 0; off >>= 1) {
        nrm += __shfl_down(nrm, off);
        nu  += __shfl_down(nu, off);
    }
    if (s == 0) {
        out[NS * SD + NS]     = (float)nu;
        out[NS * SD + NS + 1] = nrm / (float)(nu > 0 ? nu : 1);
    }
}

extern "C" void kernel_launch(void* const* d_in, const int* in_sizes, int n_in,
                              void* d_out, int out_size, void* d_ws, size_t ws_size,
                              hipStream_t stream) {
    const float* traces  = (const float*)d_in[0];
    const float* W1      = (const float*)d_in[1];
    const float* b1      = (const float*)d_in[2];
    const float* W2      = (const float*)d_in[3];
    const float* b2      = (const float*)d_in[4];
    const float* schemas = (const float*)d_in[5];
    const float* usage   = (const float*)d_in[6];
    float* out  = (float*)d_out;

    float* gacc = (float*)d_ws;                                        // 8448 B
    unsigned short* W1h = (unsigned short*)((char*)d_ws + 16384);      // 128 KB
    unsigned short* W1l = (unsigned short*)((char*)d_ws + 16384 + 131072);

    const int N = in_sizes[0] / DIM;
    const int nblk = N / TM;

    hipLaunchKernelGGL(pack_w1_kernel, dim3(DIM * HID / 256), dim3(256), 0, stream, W1, W1h, W1l);
    hipLaunchKernelGGL(zero_acc_kernel, dim3((NS * (SD + 1) + 255) / 256), dim3(256), 0, stream, gacc);
    hipLaunchKernelGGL(neo_main_kernel, dim3(nblk), dim3(256), 0, stream,
                       traces, W1h, W1l, b1, W2, b2, schemas, gacc);
    hipLaunchKernelGGL(neo_finalize_kernel, dim3(1), dim3(64), 0, stream,
                       gacc, schemas, usage, out);
}